// Round 7
// baseline (66.937 us; speedup 1.0000x reference)
//
#include <hip/hip_runtime.h>

#define IN_F 4096
#define OUT_F 11008
#define NCLUST 16
#define TOPK 1024
#define NBLK 256
#define NT 512          // 8 waves
#define GRAN_F 1024     // 4 KB granule = quarter row
#define NBUF 4          // LDS ring buffers per wave (16 KB/wave, 128 KB/block)
#define B0_ROWS 30
#define MAXROWS 44
#define MAGIC 0x5D3A7F21u

__device__ __forceinline__ float dot4(float4 a, float4 b) {
    return a.x * b.x + a.y * b.y + a.z * b.z + a.w * b.w;
}
__device__ __forceinline__ float wredsum(float v) {
    for (int o = 32; o > 0; o >>= 1) v += __shfl_down(v, o, 64);
    return v;
}
// Raw barrier: LDS-visibility only, does NOT drain vmcnt.
__device__ __forceinline__ void barrier_lds() {
    asm volatile("s_waitcnt lgkmcnt(0)" ::: "memory");
    __builtin_amdgcn_s_barrier();
}
// Async DMA of one 4 KB granule (row quarter) into LDS. 4 x 1KB insts.
__device__ __forceinline__ void stage_gq(const float* __restrict__ W,
                                         int row, int q, float* lbuf, int lane) {
    const float* src = W + (size_t)row * IN_F + q * GRAN_F + lane * 4;
    #pragma unroll
    for (int j = 0; j < 4; ++j) {
        __builtin_amdgcn_global_load_lds(
            (const __attribute__((address_space(1))) void*)(src + j * 256),
            (__attribute__((address_space(3))) void*)(lbuf + j * 256),
            16, 0, 0);
    }
}

__global__ __launch_bounds__(NT, 1) void fused_kernel(
    const float* __restrict__ x,
    const float* __restrict__ W,
    const float* __restrict__ bias,
    const float* __restrict__ centers,
    float* __restrict__ out,
    float* __restrict__ xm_ws)          // d_ws: xm[4096] + flag
{
    const int tid  = threadIdx.x;
    const int lane = tid & 63;
    const int wid  = tid >> 6;
    const int bid  = blockIdx.x;

    __shared__ __align__(16) float sxm[IN_F];                 // 16 KB: e / masked x
    __shared__ __align__(16) float wstage[8 * NBUF * GRAN_F]; // 128 KB DMA ring
    __shared__ float sredB[8];
    __shared__ float sdot[NCLUST], scsq[NCLUST];
    __shared__ unsigned int wtot4[4], weq[8];
    __shared__ unsigned int sprefix, sKrem, sG;
    __shared__ int sci;
    __shared__ float rowacc[MAXROWS][4];

    // hist overlays wstage: used only by block 0 BEFORE its staging starts.
    unsigned int* hist = (unsigned int*)wstage;   // [8][256]

    unsigned int* flag = (unsigned int*)(xm_ws + IN_F);

    // row partition: block 0 takes 30 (select-time credit); 1..13: 44; rest: 43
    int start, nb;
    if (bid == 0) { start = 0; nb = B0_ROWS; }
    else {
        const int extra = (bid - 1 < 13) ? (bid - 1) : 13;
        start = B0_ROWS + (bid - 1) * 43 + extra;
        nb = (bid <= 13) ? 44 : 43;
    }
    const int NG  = nb * 4;
    const int ngw = (NG - 1 - wid) / 8 + 1;     // granules for this wave
    float* wbase = &wstage[wid * NBUF * GRAN_F];

    const float4* x4g  = (const float4*)x;
    float4*       sxm4 = (float4*)sxm;

    if (bid == 0) {
        // ==================== SELECT (this block only) ====================
        float4 xa = x4g[tid * 2], xb = x4g[tid * 2 + 1];
        float e0 = expf(fabsf(xa.x)), e1 = expf(fabsf(xa.y));
        float e2 = expf(fabsf(xa.z)), e3 = expf(fabsf(xa.w));
        float e4 = expf(fabsf(xb.x)), e5 = expf(fabsf(xb.y));
        float e6 = expf(fabsf(xb.z)), e7 = expf(fabsf(xb.w));
        sxm4[tid * 2]     = make_float4(e0, e1, e2, e3);
        sxm4[tid * 2 + 1] = make_float4(e4, e5, e6, e7);
        {
            float s = e0 + e1 + e2 + e3 + e4 + e5 + e6 + e7;
            s = wredsum(s);
            if (lane == 0) sredB[wid] = s;
            if (tid == 0) { sprefix = 0u; sKrem = TOPK; sG = 0u; }
        }
        barrier_lds();
        const float S = sredB[0] + sredB[1] + sredB[2] + sredB[3]
                      + sredB[4] + sredB[5] + sredB[6] + sredB[7];

        // dot(c,e), sum(c^2): wave w -> clusters 2w, 2w+1
        {
            const float4* cA = (const float4*)(centers + (size_t)(2 * wid) * IN_F);
            const float4* cB = (const float4*)(centers + (size_t)(2 * wid + 1) * IN_F);
            float dA = 0, dB = 0, qA = 0, qB = 0;
            #pragma unroll
            for (int j = 0; j < 16; ++j) {
                const int idx = j * 64 + lane;
                float4 ev = sxm4[idx];
                float4 a = cA[idx], b = cB[idx];
                dA += dot4(a, ev); qA += dot4(a, a);
                dB += dot4(b, ev); qB += dot4(b, b);
            }
            dA = wredsum(dA); qA = wredsum(qA);
            dB = wredsum(dB); qB = wredsum(qB);
            if (lane == 0) {
                sdot[2 * wid] = dA;     scsq[2 * wid] = qA;
                sdot[2 * wid + 1] = dB; scsq[2 * wid + 1] = qB;
            }
        }
        barrier_lds();
        // argmin_cl [ sum(c^2) - (2/S) dot(c,e) ]  (strict <: first-min-index)
        if (wid == 0) {
            float v = (lane < NCLUST) ? (scsq[lane] - (2.0f / S) * sdot[lane]) : 3.0e38f;
            int bi = lane;
            for (int off = 8; off > 0; off >>= 1) {
                float ov = __shfl_down(v, off, 64);
                int   oi = __shfl_down(bi, off, 64);
                if (ov < v) { v = ov; bi = oi; }
            }
            if (lane == 0) sci = bi;
        }
        barrier_lds();
        const int ci = sci;

        const float4* cc4 = (const float4*)(centers + (size_t)ci * IN_F);
        float4 c0 = cc4[tid * 2], c1 = cc4[tid * 2 + 1];
        {   // clear 8x256 histogram (overlaid on wstage)
            hist[tid] = 0u; hist[tid + 512] = 0u;
            hist[tid + 1024] = 0u; hist[tid + 1536] = 0u;
        }
        barrier_lds();

        unsigned int cv[8];
        cv[0] = __float_as_uint(c0.x); cv[1] = __float_as_uint(c0.y);
        cv[2] = __float_as_uint(c0.z); cv[3] = __float_as_uint(c0.w);
        cv[4] = __float_as_uint(c1.x); cv[5] = __float_as_uint(c1.y);
        cv[6] = __float_as_uint(c1.z); cv[7] = __float_as_uint(c1.w);

        // ---- 4-pass radix select for the 1024th-largest center value ----
        for (int pass = 0; pass < 4; ++pass) {
            const int shift = 24 - 8 * pass;
            const unsigned int pfx  = sprefix;
            const unsigned int krem = sKrem;
            unsigned int* hp = &hist[wid * 256];
            #pragma unroll
            for (int k = 0; k < 8; ++k) {
                unsigned int u = cv[k];
                bool cand = (pass == 0) || ((u >> (shift + 8)) == pfx);
                if (cand) atomicAdd(&hp[(u >> shift) & 255u], 1u);
            }
            barrier_lds();
            unsigned int h = 0, s = 0;
            if (tid < 256) {
                const unsigned int b = tid;
                #pragma unroll
                for (int w = 0; w < 8; ++w) { h += hist[w * 256 + b]; hist[w * 256 + b] = 0u; }
                s = h;  // suffix-inclusive scan within wave (bin order)
                for (int off = 1; off < 64; off <<= 1) {
                    unsigned int v2 = __shfl_down(s, off, 64);
                    if (lane + off < 64) s += v2;
                }
                if (lane == 0) wtot4[wid] = s;
            }
            barrier_lds();
            if (tid < 256) {
                unsigned int add = 0;
                #pragma unroll
                for (int w2 = 0; w2 < 4; ++w2) if (w2 > wid) add += wtot4[w2];
                const unsigned int incl = s + add;    // values in bins >= b
                const unsigned int excl = incl - h;   // values in bins >  b
                if (excl < krem && krem <= incl) {
                    sprefix = (pfx << 8) | (unsigned int)tid;
                    sKrem   = krem - excl;
                }
            }
            barrier_lds();
        }
        const unsigned int T = sprefix;

        // ---- tie bookkeeping (stable: first (TOPK-G) equals in index order) ----
        unsigned int gt = 0, eq = 0;
        #pragma unroll
        for (int k = 0; k < 8; ++k) {
            gt += (cv[k] > T) ? 1u : 0u;
            eq += (cv[k] == T) ? 1u : 0u;
        }
        {
            unsigned int g = gt;
            for (int o = 32; o > 0; o >>= 1) g += __shfl_down(g, o, 64);
            if (lane == 0) atomicAdd(&sG, g);
        }
        unsigned int p = eq;
        for (int off = 1; off < 64; off <<= 1) {
            unsigned int v2 = __shfl_up(p, off, 64);
            if (lane >= off) p += v2;
        }
        if (lane == 63) weq[wid] = p;
        barrier_lds();
        unsigned int base = p - eq;
        #pragma unroll
        for (int w2 = 0; w2 < 8; ++w2) if (w2 < wid) base += weq[w2];
        const unsigned int needEq = TOPK - sG;

        // ---- emit masked x to LDS + publish to d_ws ----
        {
            float xs[8] = {xa.x, xa.y, xa.z, xa.w, xb.x, xb.y, xb.z, xb.w};
            float os[8];
            unsigned int r = 0;
            #pragma unroll
            for (int k = 0; k < 8; ++k) {
                bool sel = (cv[k] > T) || ((cv[k] == T) && (base + r < needEq));
                os[k] = sel ? xs[k] : 0.0f;
                r += (cv[k] == T) ? 1u : 0u;
            }
            sxm4[tid * 2]     = make_float4(os[0], os[1], os[2], os[3]);
            sxm4[tid * 2 + 1] = make_float4(os[4], os[5], os[6], os[7]);
            float4* xw = (float4*)xm_ws;
            xw[tid * 2]     = make_float4(os[0], os[1], os[2], os[3]);
            xw[tid * 2 + 1] = make_float4(os[4], os[5], os[6], os[7]);
        }
        __threadfence();
        __syncthreads();
        if (tid == 0)
            __hip_atomic_store(flag, MAGIC, __ATOMIC_RELEASE, __HIP_MEMORY_SCOPE_AGENT);

        // prefill this block's ring (after select; block 0 has reduced rows)
        #pragma unroll
        for (int k = 0; k < NBUF; ++k) {
            if (k < ngw) {
                const int gg = wid + 8 * k;
                stage_gq(W, start + (gg >> 2), gg & 3, wbase + k * GRAN_F, lane);
            }
        }
    } else {
        // ============ NON-SELECTOR: stage first, then wait for mask ============
        #pragma unroll
        for (int k = 0; k < NBUF; ++k) {
            if (k < ngw) {
                const int gg = wid + 8 * k;
                stage_gq(W, start + (gg >> 2), gg & 3, wbase + k * GRAN_F, lane);
            }
        }
        if (tid == 0) {
            while (__hip_atomic_load(flag, __ATOMIC_ACQUIRE,
                                     __HIP_MEMORY_SCOPE_AGENT) != MAGIC)
                __builtin_amdgcn_s_sleep(8);
        }
        __syncthreads();
        __threadfence();
        const float4* xr = (const float4*)xm_ws;
        sxm4[tid * 2]     = xr[tid * 2];
        sxm4[tid * 2 + 1] = xr[tid * 2 + 1];
        __syncthreads();
    }

    // ==================== STREAM W (all blocks) ====================
    // Wave-constant quarter: q = wid & 3  (gg = wid + 8k => gg mod 4 = wid mod 4)
    const int qw = wid & 3;
    float4 sl0 = sxm4[qw * 256 +   0 + lane];
    float4 sl1 = sxm4[qw * 256 +  64 + lane];
    float4 sl2 = sxm4[qw * 256 + 128 + lane];
    float4 sl3 = sxm4[qw * 256 + 192 + lane];

    for (int k = 0; k < ngw; ++k) {
        const int gg   = wid + 8 * k;
        const int rowl = gg >> 2;
        const int rem  = ngw - 1 - k;
        if (rem >= 3)      { asm volatile("s_waitcnt vmcnt(12)" ::: "memory"); }
        else if (rem == 2) { asm volatile("s_waitcnt vmcnt(8)"  ::: "memory"); }
        else if (rem == 1) { asm volatile("s_waitcnt vmcnt(4)"  ::: "memory"); }
        else               { asm volatile("s_waitcnt vmcnt(0)"  ::: "memory"); }
        const float4* bp = (const float4*)(wbase + (k & 3) * GRAN_F);
        float4 a0 = bp[lane];
        float4 a1 = bp[64 + lane];
        float4 a2 = bp[128 + lane];
        float4 a3 = bp[192 + lane];
        float p = dot4(a0, sl0) + dot4(a1, sl1) + dot4(a2, sl2) + dot4(a3, sl3);
        p = wredsum(p);
        if (lane == 0) rowacc[rowl][qw] = p;      // unique (row,q) writer
        asm volatile("s_waitcnt lgkmcnt(0)" ::: "memory");
        const int kn = k + NBUF;
        if (kn < ngw) {
            const int g2 = wid + 8 * kn;
            stage_gq(W, start + (g2 >> 2), g2 & 3, wbase + (k & 3) * GRAN_F, lane);
        }
    }
    __syncthreads();
    if (tid < nb) {
        const int r = start + tid;
        out[r] = rowacc[tid][0] + rowacc[tid][1] + rowacc[tid][2] + rowacc[tid][3]
               + bias[r];
    }
}

extern "C" void kernel_launch(void* const* d_in, const int* in_sizes, int n_in,
                              void* d_out, int out_size, void* d_ws, size_t ws_size,
                              hipStream_t stream) {
    const float* x       = (const float*)d_in[0];  // [1,1,4096]
    const float* weight  = (const float*)d_in[1];  // [11008,4096]
    const float* bias    = (const float*)d_in[2];  // [11008]
    const float* centers = (const float*)d_in[3];  // [16,4096]
    float* out = (float*)d_out;                    // [11008]
    float* xm  = (float*)d_ws;                     // xm[4096] + flag

    fused_kernel<<<NBLK, NT, 0, stream>>>(x, weight, bias, centers, out, xm);
}

// Round 8
// 45.401 us; speedup vs baseline: 1.4743x; 1.4743x over previous
//
#include <hip/hip_runtime.h>

#define IN_F 4096
#define OUT_F 11008
#define NCLUST 16
#define TOPK 1024
#define NT 1024
#define NW 16
#define ROWS_PB 43      // 256 blocks * 43 rows = 11008

__device__ __forceinline__ float dot4(float4 a, float4 b) {
    return a.x * b.x + a.y * b.y + a.z * b.z + a.w * b.w;
}
__device__ __forceinline__ float wredsum(float v) {
    for (int o = 32; o > 0; o >>= 1) v += __shfl_down(v, o, 64);
    return v;
}

// ---------------------------------------------------------------------------
// Kernel A: select mask (1 block, 1024 threads, 16 waves).
// exp(|x|) (no max-pass: |x| <= ~6, fp32-safe), S-trick argmin over centers,
// exact top-1024 radix select, masked x -> xm.
// ---------------------------------------------------------------------------
__global__ __launch_bounds__(NT) void select_mask_kernel(
    const float* __restrict__ x,
    const float* __restrict__ centers,
    float* __restrict__ xm)
{
    const int tid  = threadIdx.x;
    const int lane = tid & 63;
    const int wid  = tid >> 6;

    __shared__ __align__(16) float sact[IN_F];   // e values
    __shared__ unsigned int hist[NW * 256];      // per-wave private histograms
    __shared__ float swred[NW];
    __shared__ float sdot[NCLUST], scsq[NCLUST];
    __shared__ unsigned int wtot4[4], weq[NW];
    __shared__ unsigned int sprefix, sKrem, sG;
    __shared__ int sci;

    if (tid == 0) { sprefix = 0u; sKrem = TOPK; sG = 0u; }

    // ---- x load + e = exp(|x|) -> LDS + wave sums; clear histograms ----
    float4 xv = reinterpret_cast<const float4*>(x)[tid];
    float e0 = expf(fabsf(xv.x)), e1 = expf(fabsf(xv.y));
    float e2 = expf(fabsf(xv.z)), e3 = expf(fabsf(xv.w));
    reinterpret_cast<float4*>(sact)[tid] = make_float4(e0, e1, e2, e3);
    {
        float s = wredsum(e0 + e1 + e2 + e3);
        if (lane == 0) swred[wid] = s;
        hist[tid] = 0u; hist[tid + 1024] = 0u;
        hist[tid + 2048] = 0u; hist[tid + 3072] = 0u;
    }
    __syncthreads();
    float S = 0.0f;
    #pragma unroll
    for (int k = 0; k < NW; ++k) S += swred[k];   // LDS broadcast reads

    // ---- per-cluster dot(c,e), sum(c^2): wave w -> cluster w ----
    {
        const float4* cp = reinterpret_cast<const float4*>(centers + (size_t)wid * IN_F);
        const float4* a4 = reinterpret_cast<const float4*>(sact);
        float dt = 0.0f, cq = 0.0f;
        #pragma unroll
        for (int j = 0; j < 16; ++j) {
            float4 c = cp[j * 64 + lane];
            float4 a = a4[j * 64 + lane];
            dt += dot4(c, a);
            cq += dot4(c, c);
        }
        dt = wredsum(dt);
        cq = wredsum(cq);
        if (lane == 0) { sdot[wid] = dt; scsq[wid] = cq; }
    }
    __syncthreads();

    // ---- argmin_cl [ sum(c^2) - (2/S) dot(c,e) ]  (strict <: first index) ----
    if (wid == 0) {
        float v = (lane < NCLUST) ? (scsq[lane] - (2.0f / S) * sdot[lane]) : 3.0e38f;
        int bi = lane;
        for (int off = 8; off > 0; off >>= 1) {
            float ov = __shfl_down(v, off, 64);
            int   oi = __shfl_down(bi, off, 64);
            if (ov < v) { v = ov; bi = oi; }
        }
        if (lane == 0) sci = bi;
    }
    __syncthreads();

    // ---- chosen center (positive floats: uint cmp == float cmp) ----
    unsigned int cv[4];
    {
        float4 c = reinterpret_cast<const float4*>(centers + (size_t)sci * IN_F)[tid];
        cv[0] = __float_as_uint(c.x); cv[1] = __float_as_uint(c.y);
        cv[2] = __float_as_uint(c.z); cv[3] = __float_as_uint(c.w);
    }

    // ---- 4-pass radix select for the 1024th-largest value ----
    for (int pass = 0; pass < 4; ++pass) {
        const int shift = 24 - 8 * pass;
        const unsigned int pfx  = sprefix;
        const unsigned int krem = sKrem;
        unsigned int* hp = &hist[wid * 256];
        #pragma unroll
        for (int j = 0; j < 4; ++j) {
            unsigned int u = cv[j];
            bool cand = (pass == 0) || ((u >> (shift + 8)) == pfx);
            if (cand) atomicAdd(&hp[(u >> shift) & 255u], 1u);
        }
        __syncthreads();
        unsigned int h = 0, s = 0;
        if (tid < 256) {
            #pragma unroll
            for (int w = 0; w < NW; ++w) { h += hist[w * 256 + tid]; hist[w * 256 + tid] = 0u; }
            s = h;  // suffix-inclusive scan within wave (bin order)
            for (int off = 1; off < 64; off <<= 1) {
                unsigned int v2 = __shfl_down(s, off, 64);
                if (lane + off < 64) s += v2;
            }
            if (lane == 0) wtot4[wid] = s;
        }
        __syncthreads();
        if (tid < 256) {
            unsigned int add = 0;
            #pragma unroll
            for (int w2 = 0; w2 < 4; ++w2) if (w2 > wid) add += wtot4[w2];
            unsigned int incl = s + add;       // # values in bins >= tid
            unsigned int excl = incl - h;      // # values in bins >  tid
            if (excl < krem && krem <= incl) { // exactly one thread
                sprefix = (pfx << 8) | (unsigned int)tid;
                sKrem   = krem - excl;
            }
        }
        __syncthreads();
    }
    const unsigned int T = sprefix;

    // ---- tie bookkeeping (stable: first (TOPK-G) equals in index order) ----
    unsigned int gt = 0, eq = 0;
    #pragma unroll
    for (int j = 0; j < 4; ++j) {
        gt += (cv[j] > T) ? 1u : 0u;
        eq += (cv[j] == T) ? 1u : 0u;
    }
    {
        unsigned int g = wredsum(0.0f) * 0.0f + gt;  // keep it simple: reduce below
    }
    {
        unsigned int g = gt;
        for (int o = 32; o > 0; o >>= 1) g += __shfl_down(g, o, 64);
        if (lane == 0) atomicAdd(&sG, g);
    }
    unsigned int p = eq;
    for (int off = 1; off < 64; off <<= 1) {
        unsigned int v2 = __shfl_up(p, off, 64);
        if (lane >= off) p += v2;
    }
    if (lane == 63) weq[wid] = p;
    __syncthreads();
    unsigned int base = p - eq;
    #pragma unroll
    for (int w = 0; w < NW; ++w) if (w < wid) base += weq[w];
    const unsigned int needEq = TOPK - sG;

    // ---- emit masked x ----
    {
        unsigned int r = 0;
        float4 o;
        o.x = ((cv[0] > T) || ((cv[0] == T) && (base + r < needEq))) ? xv.x : 0.0f; r += (cv[0] == T);
        o.y = ((cv[1] > T) || ((cv[1] == T) && (base + r < needEq))) ? xv.y : 0.0f; r += (cv[1] == T);
        o.z = ((cv[2] > T) || ((cv[2] == T) && (base + r < needEq))) ? xv.z : 0.0f; r += (cv[2] == T);
        o.w = ((cv[3] > T) || ((cv[3] == T) && (base + r < needEq))) ? xv.w : 0.0f;
        reinterpret_cast<float4*>(xm)[tid] = o;
    }
}

// ---------------------------------------------------------------------------
// Kernel B: dense masked matvec, CU-balanced, LDS-free.
// 256 blocks (1/CU) x 1024 threads (16 waves). Block b owns rows [43b, 43b+43).
// xm slice lives in 16 float4 registers per lane; wave handles rows wid+16k.
// ---------------------------------------------------------------------------
__global__ __launch_bounds__(NT, 4) void matvec_kernel(
    const float* __restrict__ W,
    const float* __restrict__ xm,
    const float* __restrict__ bias,
    float* __restrict__ out)
{
    const int tid  = threadIdx.x;
    const int lane = tid & 63;
    const int wid  = tid >> 6;
    const int rbase = blockIdx.x * ROWS_PB;

    // per-lane xm slice: slice[j] = xm[ (j*64+lane)*4 .. +3 ]
    float4 sl[16];
    {
        const float4* xm4 = reinterpret_cast<const float4*>(xm);
        #pragma unroll
        for (int j = 0; j < 16; ++j) sl[j] = xm4[j * 64 + lane];
    }

    // rows wid, wid+16, wid+32  (43 rows: waves 0..10 get 3, 11..15 get 2)
    for (int r = wid; r < ROWS_PB; r += NW) {
        const int row = rbase + r;
        const float4* wr = reinterpret_cast<const float4*>(W + (size_t)row * IN_F);
        float acc = 0.0f;
        #pragma unroll
        for (int j = 0; j < 16; ++j) {
            acc += dot4(wr[j * 64 + lane], sl[j]);
        }
        acc = wredsum(acc);
        if (lane == 0) out[row] = acc + bias[row];
    }
}

extern "C" void kernel_launch(void* const* d_in, const int* in_sizes, int n_in,
                              void* d_out, int out_size, void* d_ws, size_t ws_size,
                              hipStream_t stream) {
    const float* x       = (const float*)d_in[0];  // [1,1,4096]
    const float* weight  = (const float*)d_in[1];  // [11008,4096]
    const float* bias    = (const float*)d_in[2];  // [11008]
    const float* centers = (const float*)d_in[3];  // [16,4096]
    float* out = (float*)d_out;                    // [11008]
    float* xm  = (float*)d_ws;                     // 4096 floats scratch

    select_mask_kernel<<<1, NT, 0, stream>>>(x, centers, xm);
    matvec_kernel<<<256, NT, 0, stream>>>(weight, xm, bias, out);
}